// Round 2
// baseline (5495.030 us; speedup 1.0000x reference)
//
#include <hip/hip_runtime.h>

typedef _Float16 v8h __attribute__((ext_vector_type(8)));
typedef float    v4f __attribute__((ext_vector_type(4)));

#define LO_SCALE 2048.0f
#define LO_INV   4.8828125e-4f

__device__ __forceinline__ float fast_rcp(float x) { return __builtin_amdgcn_rcpf(x); }
__device__ __forceinline__ float sigmoid_f(float x) { return fast_rcp(1.0f + __expf(-x)); }
__device__ __forceinline__ float tanh_f(float x) {
    float e = __expf(-2.0f * fabsf(x));
    float r = (1.0f - e) * fast_rcp(1.0f + e);
    return copysignf(r, x);
}

// ---------------------------------------------------------------------------
// prep: fused, transposed f16 weight matrix WT[g][kout][448], hi + scaled-lo
// K segments: [Wt0 | Wt1 | Wt2 | Ws | U | Zt | Zs[ZS_IDX[g]]]
// ---------------------------------------------------------------------------
__global__ void prep_wt(const float* __restrict__ Wt, const float* __restrict__ Ws,
                        const float* __restrict__ U,  const float* __restrict__ Zt,
                        const float* __restrict__ Zs,
                        _Float16* __restrict__ WTh, _Float16* __restrict__ WTl)
{
    int idx = blockIdx.x * 256 + threadIdx.x;
    if (idx >= 9 * 64 * 448) return;
    int g    = idx / 28672;
    int rem  = idx - g * 28672;
    int kout = rem / 448;
    int k    = rem - kout * 448;
    int seg  = k >> 6, kl = k & 63;
    const int zsidx[9] = {0, 1, 1, 3, 4, 5, 6, 7, 8};
    float v;
    if (seg < 3)       v = Wt[g * 12288 + (seg * 64 + kl) * 64 + kout];
    else if (seg == 3) v = Ws[g * 4096 + kl * 64 + kout];
    else if (seg == 4) v = U [g * 4096 + kl * 64 + kout];
    else if (seg == 5) v = Zt[g * 4096 + kl * 64 + kout];
    else               v = Zs[zsidx[g] * 4096 + kl * 64 + kout];
    _Float16 hi = (_Float16)v;
    WTh[idx] = hi;
    WTl[idx] = (_Float16)((v - (float)hi) * LO_SCALE);
}

// ---------------------------------------------------------------------------
// f32 -> f16 hi/lo split of encoder inputs, zero-padded to 2048 rows
// ---------------------------------------------------------------------------
__global__ void conv_enc(const float* __restrict__ X,
                         _Float16* __restrict__ Yh, _Float16* __restrict__ Yl)
{
    long i = ((long)blockIdx.x * 256 + threadIdx.x) * 8;   // < 2048*4096
    v8h oh, ol;
    if (i < 2016L * 4096) {
        const float4* p = (const float4*)(X + i);
        float4 a = p[0], b = p[1];
        float xv[8] = {a.x, a.y, a.z, a.w, b.x, b.y, b.z, b.w};
#pragma unroll
        for (int j = 0; j < 8; ++j) {
            _Float16 hi = (_Float16)xv[j];
            oh[j] = hi;
            ol[j] = (_Float16)((xv[j] - (float)hi) * LO_SCALE);
        }
    } else {
#pragma unroll
        for (int j = 0; j < 8; ++j) { oh[j] = (_Float16)0.0f; ol[j] = (_Float16)0.0f; }
    }
    *(v8h*)(Yh + i) = oh;
    *(v8h*)(Yl + i) = ol;
}

// ---------------------------------------------------------------------------
// transpose weights_in [k][n] f32 -> winT hi/lo [n][k] f16
// ---------------------------------------------------------------------------
__global__ void transp_win(const float* __restrict__ W,
                           _Float16* __restrict__ Th, _Float16* __restrict__ Tl)
{
    __shared__ float tile[64][65];
    int k0 = blockIdx.x * 64, n0 = blockIdx.y * 64;
    int tid = threadIdx.x;
    int cc = tid & 63;
#pragma unroll
    for (int p = 0; p < 16; ++p) {
        int r = p * 4 + (tid >> 6);
        tile[cc][r] = W[(size_t)(k0 + r) * 4096 + n0 + cc];
    }
    __syncthreads();
#pragma unroll
    for (int p = 0; p < 16; ++p) {
        int r = p * 4 + (tid >> 6);
        float v = tile[r][cc];
        _Float16 hi = (_Float16)v;
        Th[(size_t)(n0 + r) * 4096 + k0 + cc] = hi;
        Tl[(size_t)(n0 + r) * 4096 + k0 + cc] = (_Float16)((v - (float)hi) * LO_SCALE);
    }
}

// ---------------------------------------------------------------------------
// h0 = enc @ winT^T + bias, compensated 3-pass f16 MFMA (f32-exact result)
// 128x128 tile, BK=32; writes f32 (c0) and f16 (hA)
// ---------------------------------------------------------------------------
__global__ __launch_bounds__(256, 2) void gemm_h0(
    const _Float16* __restrict__ Ah, const _Float16* __restrict__ Al,
    const _Float16* __restrict__ Bh, const _Float16* __restrict__ Bl,
    const float* __restrict__ bias, float* __restrict__ h0f, _Float16* __restrict__ h0h)
{
    __shared__ __attribute__((aligned(16))) _Float16 Ash[128 * 40];
    __shared__ __attribute__((aligned(16))) _Float16 Asl[128 * 40];
    __shared__ __attribute__((aligned(16))) _Float16 Bsh[128 * 40];
    __shared__ __attribute__((aligned(16))) _Float16 Bsl[128 * 40];
    // XCD-banded swizzle: each XCD works one nt-band of 4, all 16 mt
    int id = blockIdx.x;                 // 0..511
    int xcd = id & 7, local = id >> 3;   // local 0..63
    int nt = xcd * 4 + (local >> 4);     // 0..31
    int mt = local & 15;                 // 0..15
    int tid = threadIdx.x, wave = tid >> 6, lane = tid & 63;
    int col = lane & 15, quad = lane >> 4;

    v4f accm[2][8], accc[2][8];
#pragma unroll
    for (int mi = 0; mi < 2; ++mi)
#pragma unroll
        for (int ni = 0; ni < 8; ++ni) {
            v4f z = {0.f, 0.f, 0.f, 0.f};
            accm[mi][ni] = z; accc[mi][ni] = z;
        }

    for (int kt = 0; kt < 128; ++kt) {
        __syncthreads();
#pragma unroll
        for (int p = 0; p < 2; ++p) {
            int idx = p * 2048 + tid * 8;
            int r = idx >> 5, c = idx & 31;
            size_t ga = (size_t)(mt * 128 + r) * 4096 + kt * 32 + c;
            size_t gb = (size_t)(nt * 128 + r) * 4096 + kt * 32 + c;
            *(v8h*)(&Ash[r * 40 + c]) = *(const v8h*)(Ah + ga);
            *(v8h*)(&Asl[r * 40 + c]) = *(const v8h*)(Al + ga);
            *(v8h*)(&Bsh[r * 40 + c]) = *(const v8h*)(Bh + gb);
            *(v8h*)(&Bsl[r * 40 + c]) = *(const v8h*)(Bl + gb);
        }
        __syncthreads();
        v8h afh[2], afl[2];
#pragma unroll
        for (int mi = 0; mi < 2; ++mi) {
            afh[mi] = *(const v8h*)(&Ash[(wave * 32 + mi * 16 + col) * 40 + quad * 8]);
            afl[mi] = *(const v8h*)(&Asl[(wave * 32 + mi * 16 + col) * 40 + quad * 8]);
        }
#pragma unroll
        for (int ni = 0; ni < 8; ++ni) {
            v8h bfh = *(const v8h*)(&Bsh[(ni * 16 + col) * 40 + quad * 8]);
            v8h bfl = *(const v8h*)(&Bsl[(ni * 16 + col) * 40 + quad * 8]);
#pragma unroll
            for (int mi = 0; mi < 2; ++mi) {
                accm[mi][ni] = __builtin_amdgcn_mfma_f32_16x16x32_f16(afh[mi], bfh, accm[mi][ni], 0, 0, 0);
                accc[mi][ni] = __builtin_amdgcn_mfma_f32_16x16x32_f16(afl[mi], bfh, accc[mi][ni], 0, 0, 0);
                accc[mi][ni] = __builtin_amdgcn_mfma_f32_16x16x32_f16(afh[mi], bfl, accc[mi][ni], 0, 0, 0);
            }
        }
    }
#pragma unroll
    for (int mi = 0; mi < 2; ++mi)
#pragma unroll
        for (int ni = 0; ni < 8; ++ni)
#pragma unroll
            for (int i = 0; i < 4; ++i) {
                int row  = mt * 128 + wave * 32 + mi * 16 + quad * 4 + i;
                int ccol = nt * 128 + ni * 16 + col;
                if (row < 2016) {
                    float v = accm[mi][ni][i] + accc[mi][ni][i] * LO_INV + bias[ccol];
                    h0f[(size_t)row * 4096 + ccol] = v;
                    h0h[(size_t)row * 4096 + ccol] = (_Float16)v;
                }
            }
}

// ---------------------------------------------------------------------------
// g_t = mean over t (63);  g_s = mean over n (64)
// ---------------------------------------------------------------------------
__global__ void mean_t(const float* __restrict__ h0, float* __restrict__ gt32,
                       _Float16* __restrict__ gt16)
{
    int i = blockIdx.x * 256 + threadIdx.x;       // < 32*4096
    int b = i >> 12, c = i & 4095;
    float s = 0.f;
    for (int t = 0; t < 63; ++t) s += h0[((size_t)b * 63 + t) * 4096 + c];
    s *= (1.0f / 63.0f);
    gt32[i] = s; gt16[i] = (_Float16)s;
}

__global__ void mean_n(const float* __restrict__ h0, float* __restrict__ gs32,
                       _Float16* __restrict__ gs16)
{
    int i = blockIdx.x * 256 + threadIdx.x;       // < 2016*64
    int row = i >> 6, k = i & 63;
    float s = 0.f;
    for (int n = 0; n < 64; ++n) s += h0[(size_t)row * 4096 + n * 64 + k];
    s *= (1.0f / 64.0f);
    gs32[i] = s; gs16[i] = (_Float16)s;
}

// ---------------------------------------------------------------------------
// fused recurrent step: one workgroup per (b,t) tile; wave-per-gate-group
// pre[g] = A(64x448) @ (WT_hi[g] + WT_lo[g]/2048)(448x64)^T + bias[g]
// split-B: two K-phases per gate sharing one accumulator
// ---------------------------------------------------------------------------
__global__ __launch_bounds__(256, 2) void recur(
    const _Float16* __restrict__ h_in, _Float16* __restrict__ h_out,
    const float* __restrict__ c_in, float* __restrict__ c_out,
    const _Float16* __restrict__ p16, const _Float16* __restrict__ gt16,
    const _Float16* __restrict__ gs16, const float* __restrict__ gt32,
    const float* __restrict__ gs32, const _Float16* __restrict__ WTh,
    const _Float16* __restrict__ WTl,
    const float* __restrict__ bias9, float* __restrict__ outf, int last)
{
    __shared__ __attribute__((aligned(16))) _Float16 lds_htb[64 * 72];
    __shared__ __attribute__((aligned(16))) _Float16 lds_h  [65 * 72];   // row 0 = zeros
    __shared__ __attribute__((aligned(16))) _Float16 lds_hta[64 * 72];
    __shared__ __attribute__((aligned(16))) _Float16 lds_p  [64 * 72];
    __shared__ __attribute__((aligned(16))) _Float16 lds_gt [64 * 72];
    __shared__ __attribute__((aligned(16))) _Float16 lds_gs [64];
    __shared__ __attribute__((aligned(16))) float    c_red  [64 * 66];

    int blk = blockIdx.x;
    int b = blk / 63, t = blk - b * 63;
    size_t toff = (size_t)blk * 4096;
    int tid = threadIdx.x;
    int wave = tid >> 6, lane = tid & 63;
    int col = lane & 15, quad = lane >> 4;

    v8h zero8;
#pragma unroll
    for (int j = 0; j < 8; ++j) zero8[j] = (_Float16)0.0f;

    const _Float16* s_htb = (t > 0)  ? h_in + toff - 4096 : nullptr;
    const _Float16* s_hta = (t < 62) ? h_in + toff + 4096 : nullptr;
    const _Float16* s_h   = h_in + toff;
    const _Float16* s_p   = p16 + toff;
    const _Float16* s_gt  = gt16 + (size_t)b * 4096;

#pragma unroll
    for (int p2 = 0; p2 < 2; ++p2) {
        int idx = p2 * 2048 + tid * 8;
        int r = idx >> 6, c = idx & 63;
        v8h v;
        v = s_htb ? *(const v8h*)(s_htb + idx) : zero8;
        *(v8h*)(&lds_htb[r * 72 + c]) = v;
        v = s_hta ? *(const v8h*)(s_hta + idx) : zero8;
        *(v8h*)(&lds_hta[r * 72 + c]) = v;
        *(v8h*)(&lds_h[(r + 1) * 72 + c]) = *(const v8h*)(s_h + idx);
        *(v8h*)(&lds_p[r * 72 + c])       = *(const v8h*)(s_p + idx);
        *(v8h*)(&lds_gt[r * 72 + c])      = *(const v8h*)(s_gt + idx);
    }
    if (tid < 8)  *(v8h*)(&lds_h[tid * 8]) = zero8;                       // zero row
    if (tid >= 8 && tid < 16)
        *(v8h*)(&lds_gs[(tid - 8) * 8]) = *(const v8h*)(gs16 + (size_t)blk * 64 + (tid - 8) * 8);
    for (int i2 = tid; i2 < 64 * 66; i2 += 256) c_red[i2] = 0.0f;
    __syncthreads();

    int nglist, glist[3];
    if (wave == 0)      { nglist = 2; glist[0] = 0; glist[1] = 8; glist[2] = 8; }
    else if (wave == 1) { nglist = 3; glist[0] = 1; glist[1] = 2; glist[2] = 7; }
    else if (wave == 2) { nglist = 2; glist[0] = 3; glist[1] = 4; glist[2] = 4; }
    else                { nglist = 2; glist[0] = 5; glist[1] = 6; glist[2] = 6; }

    const _Float16* segbase[7] = {lds_htb, lds_h + 72, lds_hta, lds_h, lds_p, lds_gt, lds_gs};
    const int segstride[7] = {72, 72, 72, 72, 72, 72, 0};

    v4f carry[4][4];   // i_n (wave0) or o_n (wave1)

    for (int gi = 0; gi < nglist; ++gi) {
        int g = glist[gi];
        v4f acc[4][4];
#pragma unroll
        for (int mi = 0; mi < 4; ++mi)
#pragma unroll
            for (int ni = 0; ni < 4; ++ni) {
                v4f z = {0.f, 0.f, 0.f, 0.f};
                acc[mi][ni] = z;
            }
        for (int ph = 0; ph < 2; ++ph) {
            const _Float16* wg = (ph == 0 ? WTl : WTh) + (size_t)g * 28672;
#pragma unroll
            for (int ks = 0; ks < 14; ++ks) {
                int seg   = ks >> 1;
                int koff  = (ks & 1) * 32 + quad * 8;
                int kglob = ks * 32 + quad * 8;
                v8h bf[4];
#pragma unroll
                for (int ni = 0; ni < 4; ++ni)
                    bf[ni] = *(const v8h*)(wg + (size_t)(ni * 16 + col) * 448 + kglob);
                v8h af[4];
#pragma unroll
                for (int mi = 0; mi < 4; ++mi) {
                    int m = mi * 16 + col;
                    af[mi] = *(const v8h*)(segbase[seg] + m * segstride[seg] + koff);
                }
#pragma unroll
                for (int mi = 0; mi < 4; ++mi)
#pragma unroll
                    for (int ni = 0; ni < 4; ++ni)
                        acc[mi][ni] = __builtin_amdgcn_mfma_f32_16x16x32_f16(af[mi], bf[ni], acc[mi][ni], 0, 0, 0);
            }
            if (ph == 0) {        // scale lo contribution, add bias
                const float* bg = bias9 + g * 4096;
#pragma unroll
                for (int mi = 0; mi < 4; ++mi)
#pragma unroll
                    for (int ni = 0; ni < 4; ++ni)
#pragma unroll
                        for (int i = 0; i < 4; ++i) {
                            int n = mi * 16 + quad * 4 + i;
                            acc[mi][ni][i] = acc[mi][ni][i] * LO_INV + bg[n * 64 + ni * 16 + col];
                        }
            }
        }

        if (g == 0 || g == 7) {               // i_n / o_n: save activation
#pragma unroll
            for (int mi = 0; mi < 4; ++mi)
#pragma unroll
                for (int ni = 0; ni < 4; ++ni)
#pragma unroll
                    for (int i = 0; i < 4; ++i)
                        carry[mi][ni][i] = sigmoid_f(acc[mi][ni][i]);
        } else if (g == 8) {                  // c_n * i_n
#pragma unroll
            for (int mi = 0; mi < 4; ++mi)
#pragma unroll
                for (int ni = 0; ni < 4; ++ni)
#pragma unroll
                    for (int i = 0; i < 4; ++i) {
                        int n = mi * 16 + quad * 4 + i, kk = ni * 16 + col;
                        float v = tanh_f(acc[mi][ni][i]) * carry[mi][ni][i];
                        atomicAdd(&c_red[n * 66 + kk], v);
                    }
        } else {                              // forget gates: act * partner
            const float* pb = nullptr;
            if (g == 1)      pb = (t > 0)  ? c_in + toff - 4096 : nullptr;
            else if (g == 2 || g == 4) pb = c_in + toff;
            else if (g == 3) pb = (t < 62) ? c_in + toff + 4096 : nullptr;
            else if (g == 5) pb = gt32 + (size_t)b * 4096;
            float gsv[4];
            if (g == 6) {
                const float* gr = gs32 + (size_t)blk * 64;
#pragma unroll
                for (int ni = 0; ni < 4; ++ni) gsv[ni] = gr[ni * 16 + col];
            }
#pragma unroll
            for (int mi = 0; mi < 4; ++mi)
#pragma unroll
                for (int ni = 0; ni < 4; ++ni)
#pragma unroll
                    for (int i = 0; i < 4; ++i) {
                        int n = mi * 16 + quad * 4 + i, kk = ni * 16 + col;
                        float act = sigmoid_f(acc[mi][ni][i]);
                        float val;
                        if (g == 6)      val = gsv[ni];
                        else if (g == 4) val = (n > 0) ? pb[(n - 1) * 64 + kk] : 0.0f;
                        else             val = pb ? pb[n * 64 + kk] : 0.0f;
                        atomicAdd(&c_red[n * 66 + kk], act * val);
                    }
        }
    }
    __syncthreads();

    if (wave == 1) {                          // h = o_n * tanh(c)
#pragma unroll
        for (int mi = 0; mi < 4; ++mi)
#pragma unroll
            for (int ni = 0; ni < 4; ++ni)
#pragma unroll
                for (int i = 0; i < 4; ++i) {
                    int n = mi * 16 + quad * 4 + i, kk = ni * 16 + col;
                    float cv = c_red[n * 66 + kk];
                    float hv = carry[mi][ni][i] * tanh_f(cv);
                    if (last) outf[toff + n * 64 + kk] = hv;
                    else      h_out[toff + n * 64 + kk] = (_Float16)hv;
                }
    } else if (wave == 2 && !last) {          // write new c
#pragma unroll
        for (int mi = 0; mi < 4; ++mi)
#pragma unroll
            for (int ni = 0; ni < 4; ++ni)
#pragma unroll
                for (int i = 0; i < 4; ++i) {
                    int n = mi * 16 + quad * 4 + i, kk = ni * 16 + col;
                    c_out[toff + n * 64 + kk] = c_red[n * 66 + kk];
                }
    }
}

// ---------------------------------------------------------------------------
extern "C" void kernel_launch(void* const* d_in, const int* in_sizes, int n_in,
                              void* d_out, int out_size, void* d_ws, size_t ws_size,
                              hipStream_t stream)
{
    const float* enc = (const float*)d_in[0];
    // d_in[1] (decoder_inputs) is unused by the reference
    const float* win = (const float*)d_in[2];
    const float* bin = (const float*)d_in[3];
    const float* U   = (const float*)d_in[4];
    const float* Wt  = (const float*)d_in[5];
    const float* Ws  = (const float*)d_in[6];
    const float* Zt  = (const float*)d_in[7];
    const float* Zs  = (const float*)d_in[8];
    const float* bb  = (const float*)d_in[9];
    float* out = (float*)d_out;
    char* ws = (char*)d_ws;

    _Float16* enc_hi = (_Float16*)(ws);                   // 16,777,216
    _Float16* enc_lo = (_Float16*)(ws + 16777216);        // 16,777,216
    _Float16* winT_h = (_Float16*)(ws + 33554432);        // 33,554,432
    _Float16* winT_l = (_Float16*)(ws + 67108864);        // 33,554,432 (dead after gemm)
    float*    c0     = (float*)   (ws + 100663296);       // 33,030,144
    _Float16* hA     = (_Float16*)(ws + 133693440);       // 16,515,072 (= p)
    float*    gt32   = (float*)   (ws + 150208512);       // 524,288
    _Float16* gt16   = (_Float16*)(ws + 150732800);       // 262,144
    float*    gs32   = (float*)   (ws + 150994944);       // 516,096
    _Float16* gs16   = (_Float16*)(ws + 151511040);       // 258,048
    _Float16* WT_h   = (_Float16*)(ws + 151769088);       // 516,096
    _Float16* WT_l   = (_Float16*)(ws + 152285184);       // 516,096 ; end 152,801,280
    // hB/hC alias winT_lo space (dead after gemm_h0)
    _Float16* hB     = (_Float16*)(ws + 67108864);        // 16,515,072
    _Float16* hC     = (_Float16*)(ws + 83886080);        // 16,515,072 (ends 100,401,152 < c0)
    float* c1 = out;  // d_out doubles as the second c ping-pong buffer

    prep_wt   <<<1008, 256, 0, stream>>>(Wt, Ws, U, Zt, Zs, WT_h, WT_l);
    conv_enc  <<<4096, 256, 0, stream>>>(enc, enc_hi, enc_lo);
    transp_win<<<dim3(64, 64), 256, 0, stream>>>(win, winT_h, winT_l);
    gemm_h0   <<<512, 256, 0, stream>>>(enc_hi, enc_lo, winT_h, winT_l, bin, c0, hA);
    mean_t    <<<512, 256, 0, stream>>>(c0, gt32, gt16);
    mean_n    <<<504, 256, 0, stream>>>(c0, gs32, gs16);
    recur<<<2016, 256, 0, stream>>>(hA, hB, c0, c1, hA, gt16, gs16, gt32, gs32, WT_h, WT_l, bb, out, 0);
    recur<<<2016, 256, 0, stream>>>(hB, hC, c1, c0, hA, gt16, gs16, gt32, gs32, WT_h, WT_l, bb, out, 0);
    recur<<<2016, 256, 0, stream>>>(hC, nullptr, c0, nullptr, hA, gt16, gs16, gt32, gs32, WT_h, WT_l, bb, out, 1);
}

// Round 3
// 2186.188 us; speedup vs baseline: 2.5135x; 2.5135x over previous
//
#include <hip/hip_runtime.h>

typedef _Float16 v8h __attribute__((ext_vector_type(8)));
typedef float    v4f __attribute__((ext_vector_type(4)));

#define LO_SCALE 2048.0f
#define LO_INV   4.8828125e-4f

__device__ __forceinline__ float fast_rcp(float x) { return __builtin_amdgcn_rcpf(x); }
__device__ __forceinline__ float sigmoid_f(float x) { return fast_rcp(1.0f + __expf(-x)); }
__device__ __forceinline__ float tanh_f(float x) {
    float e = __expf(-2.0f * fabsf(x));
    float r = (1.0f - e) * fast_rcp(1.0f + e);
    return copysignf(r, x);
}

// ---------------------------------------------------------------------------
// prep: fused, transposed f16 weight matrix WT[g][kout][448]
// K segments: [Wt0 | Wt1 | Wt2 | Ws | U | Zt | Zs[ZS_IDX[g]]]
// ---------------------------------------------------------------------------
__global__ void prep_wt(const float* __restrict__ Wt, const float* __restrict__ Ws,
                        const float* __restrict__ U,  const float* __restrict__ Zt,
                        const float* __restrict__ Zs, _Float16* __restrict__ WTh)
{
    int idx = blockIdx.x * 256 + threadIdx.x;
    if (idx >= 9 * 64 * 448) return;
    int g    = idx / 28672;
    int rem  = idx - g * 28672;
    int kout = rem / 448;
    int k    = rem - kout * 448;
    int seg  = k >> 6, kl = k & 63;
    const int zsidx[9] = {0, 1, 1, 3, 4, 5, 6, 7, 8};
    float v;
    if (seg < 3)       v = Wt[g * 12288 + (seg * 64 + kl) * 64 + kout];
    else if (seg == 3) v = Ws[g * 4096 + kl * 64 + kout];
    else if (seg == 4) v = U [g * 4096 + kl * 64 + kout];
    else if (seg == 5) v = Zt[g * 4096 + kl * 64 + kout];
    else               v = Zs[zsidx[g] * 4096 + kl * 64 + kout];
    WTh[idx] = (_Float16)v;
}

// ---------------------------------------------------------------------------
// f32 -> f16 hi/lo split of encoder inputs, zero-padded to 2048 rows
// ---------------------------------------------------------------------------
__global__ void conv_enc(const float* __restrict__ X,
                         _Float16* __restrict__ Yh, _Float16* __restrict__ Yl)
{
    long i = ((long)blockIdx.x * 256 + threadIdx.x) * 8;   // < 2048*4096
    v8h oh, ol;
    if (i < 2016L * 4096) {
        const float4* p = (const float4*)(X + i);
        float4 a = p[0], b = p[1];
        float xv[8] = {a.x, a.y, a.z, a.w, b.x, b.y, b.z, b.w};
#pragma unroll
        for (int j = 0; j < 8; ++j) {
            _Float16 hi = (_Float16)xv[j];
            oh[j] = hi;
            ol[j] = (_Float16)((xv[j] - (float)hi) * LO_SCALE);
        }
    } else {
#pragma unroll
        for (int j = 0; j < 8; ++j) { oh[j] = (_Float16)0.0f; ol[j] = (_Float16)0.0f; }
    }
    *(v8h*)(Yh + i) = oh;
    *(v8h*)(Yl + i) = ol;
}

// ---------------------------------------------------------------------------
// transpose weights_in [k][n] f32 -> winT hi/lo [n][k] f16
// ---------------------------------------------------------------------------
__global__ void transp_win(const float* __restrict__ W,
                           _Float16* __restrict__ Th, _Float16* __restrict__ Tl)
{
    __shared__ float tile[64][65];
    int k0 = blockIdx.x * 64, n0 = blockIdx.y * 64;
    int tid = threadIdx.x;
    int cc = tid & 63;
#pragma unroll
    for (int p = 0; p < 16; ++p) {
        int r = p * 4 + (tid >> 6);
        tile[cc][r] = W[(size_t)(k0 + r) * 4096 + n0 + cc];
    }
    __syncthreads();
#pragma unroll
    for (int p = 0; p < 16; ++p) {
        int r = p * 4 + (tid >> 6);
        float v = tile[r][cc];
        _Float16 hi = (_Float16)v;
        Th[(size_t)(n0 + r) * 4096 + k0 + cc] = hi;
        Tl[(size_t)(n0 + r) * 4096 + k0 + cc] = (_Float16)((v - (float)hi) * LO_SCALE);
    }
}

// ---------------------------------------------------------------------------
// h0 = enc @ winT^T + bias, compensated 3-pass f16 MFMA (f32-exact result)
// 128x128 tile, BK=32; writes f32 (c0) and f16 (hA)
// ---------------------------------------------------------------------------
__global__ __launch_bounds__(256, 2) void gemm_h0(
    const _Float16* __restrict__ Ah, const _Float16* __restrict__ Al,
    const _Float16* __restrict__ Bh, const _Float16* __restrict__ Bl,
    const float* __restrict__ bias, float* __restrict__ h0f, _Float16* __restrict__ h0h)
{
    __shared__ __attribute__((aligned(16))) _Float16 Ash[128 * 40];
    __shared__ __attribute__((aligned(16))) _Float16 Asl[128 * 40];
    __shared__ __attribute__((aligned(16))) _Float16 Bsh[128 * 40];
    __shared__ __attribute__((aligned(16))) _Float16 Bsl[128 * 40];
    int id = blockIdx.x;                 // 0..511
    int xcd = id & 7, local = id >> 3;   // local 0..63
    int nt = xcd * 4 + (local >> 4);     // 0..31
    int mt = local & 15;                 // 0..15
    int tid = threadIdx.x, wave = tid >> 6, lane = tid & 63;
    int col = lane & 15, quad = lane >> 4;

    v4f accm[2][8], accc[2][8];
#pragma unroll
    for (int mi = 0; mi < 2; ++mi)
#pragma unroll
        for (int ni = 0; ni < 8; ++ni) {
            v4f z = {0.f, 0.f, 0.f, 0.f};
            accm[mi][ni] = z; accc[mi][ni] = z;
        }

    for (int kt = 0; kt < 128; ++kt) {
        __syncthreads();
#pragma unroll
        for (int p = 0; p < 2; ++p) {
            int idx = p * 2048 + tid * 8;
            int r = idx >> 5, c = idx & 31;
            size_t ga = (size_t)(mt * 128 + r) * 4096 + kt * 32 + c;
            size_t gb = (size_t)(nt * 128 + r) * 4096 + kt * 32 + c;
            *(v8h*)(&Ash[r * 40 + c]) = *(const v8h*)(Ah + ga);
            *(v8h*)(&Asl[r * 40 + c]) = *(const v8h*)(Al + ga);
            *(v8h*)(&Bsh[r * 40 + c]) = *(const v8h*)(Bh + gb);
            *(v8h*)(&Bsl[r * 40 + c]) = *(const v8h*)(Bl + gb);
        }
        __syncthreads();
        v8h afh[2], afl[2];
#pragma unroll
        for (int mi = 0; mi < 2; ++mi) {
            afh[mi] = *(const v8h*)(&Ash[(wave * 32 + mi * 16 + col) * 40 + quad * 8]);
            afl[mi] = *(const v8h*)(&Asl[(wave * 32 + mi * 16 + col) * 40 + quad * 8]);
        }
#pragma unroll
        for (int ni = 0; ni < 8; ++ni) {
            v8h bfh = *(const v8h*)(&Bsh[(ni * 16 + col) * 40 + quad * 8]);
            v8h bfl = *(const v8h*)(&Bsl[(ni * 16 + col) * 40 + quad * 8]);
#pragma unroll
            for (int mi = 0; mi < 2; ++mi) {
                accm[mi][ni] = __builtin_amdgcn_mfma_f32_16x16x32_f16(afh[mi], bfh, accm[mi][ni], 0, 0, 0);
                accc[mi][ni] = __builtin_amdgcn_mfma_f32_16x16x32_f16(afl[mi], bfh, accc[mi][ni], 0, 0, 0);
                accc[mi][ni] = __builtin_amdgcn_mfma_f32_16x16x32_f16(afh[mi], bfl, accc[mi][ni], 0, 0, 0);
            }
        }
    }
#pragma unroll
    for (int mi = 0; mi < 2; ++mi)
#pragma unroll
        for (int ni = 0; ni < 8; ++ni)
#pragma unroll
            for (int i = 0; i < 4; ++i) {
                int row  = mt * 128 + wave * 32 + mi * 16 + quad * 4 + i;
                int ccol = nt * 128 + ni * 16 + col;
                if (row < 2016) {
                    float v = accm[mi][ni][i] + accc[mi][ni][i] * LO_INV + bias[ccol];
                    h0f[(size_t)row * 4096 + ccol] = v;
                    h0h[(size_t)row * 4096 + ccol] = (_Float16)v;
                }
            }
}

// ---------------------------------------------------------------------------
// g_t = mean over t (63);  g_s = mean over n (64)
// ---------------------------------------------------------------------------
__global__ void mean_t(const float* __restrict__ h0, float* __restrict__ gt32,
                       _Float16* __restrict__ gt16)
{
    int i = blockIdx.x * 256 + threadIdx.x;       // < 32*4096
    int b = i >> 12, c = i & 4095;
    float s = 0.f;
    for (int t = 0; t < 63; ++t) s += h0[((size_t)b * 63 + t) * 4096 + c];
    s *= (1.0f / 63.0f);
    gt32[i] = s; gt16[i] = (_Float16)s;
}

__global__ void mean_n(const float* __restrict__ h0, float* __restrict__ gs32,
                       _Float16* __restrict__ gs16)
{
    int i = blockIdx.x * 256 + threadIdx.x;       // < 2016*64
    int row = i >> 6, k = i & 63;
    float s = 0.f;
    for (int n = 0; n < 64; ++n) s += h0[(size_t)row * 4096 + n * 64 + k];
    s *= (1.0f / 64.0f);
    gs32[i] = s; gs16[i] = (_Float16)s;
}

// ---------------------------------------------------------------------------
// fused recurrent step, 9 waves = one gate per wave (no cross-gate registers,
// no spills). pre[g] = A(64x448) @ WT[g](448x64)^T + bias[g]
// A segs: [h(t-1) | h(t) | h(t+1) | h(n-1) | p | g_t | g_s bcast]
// ---------------------------------------------------------------------------
__global__ __launch_bounds__(576) void recur(
    const _Float16* __restrict__ h_in, _Float16* __restrict__ h_out,
    const float* __restrict__ c_in, float* __restrict__ c_out,
    const _Float16* __restrict__ p16, const _Float16* __restrict__ gt16,
    const _Float16* __restrict__ gs16, const float* __restrict__ gt32,
    const float* __restrict__ gs32, const _Float16* __restrict__ WTh,
    const float* __restrict__ bias9, float* __restrict__ outf, int last)
{
    __shared__ __attribute__((aligned(16))) _Float16 lds_htb[64 * 72];
    __shared__ __attribute__((aligned(16))) _Float16 lds_h  [65 * 72];   // row 0 = zeros
    __shared__ __attribute__((aligned(16))) _Float16 lds_hta[64 * 72];
    __shared__ __attribute__((aligned(16))) _Float16 lds_p  [64 * 72];
    __shared__ __attribute__((aligned(16))) _Float16 lds_gt [64 * 72];
    __shared__ __attribute__((aligned(16))) _Float16 lds_gs [64];
    __shared__ __attribute__((aligned(16))) float    c_red  [64 * 66];
    __shared__ __attribute__((aligned(16))) _Float16 i_lds  [64 * 68];

    int blk = blockIdx.x;
    int b = blk / 63, t = blk - b * 63;
    size_t toff = (size_t)blk * 4096;
    int tid = threadIdx.x;
    int wave = tid >> 6, lane = tid & 63;
    int col = lane & 15, quad = lane >> 4;

    v8h zero8;
#pragma unroll
    for (int j = 0; j < 8; ++j) zero8[j] = (_Float16)0.0f;

    // ---- stage A operands into LDS (512 threads), row stride 72 (2-way = free)
    if (tid < 512) {
        int idx = tid * 8;
        int r = idx >> 6, c = idx & 63;
        const _Float16* s_htb = (t > 0)  ? h_in + toff - 4096 : nullptr;
        const _Float16* s_hta = (t < 62) ? h_in + toff + 4096 : nullptr;
        v8h v;
        v = s_htb ? *(const v8h*)(s_htb + idx) : zero8;
        *(v8h*)(&lds_htb[r * 72 + c]) = v;
        v = s_hta ? *(const v8h*)(s_hta + idx) : zero8;
        *(v8h*)(&lds_hta[r * 72 + c]) = v;
        *(v8h*)(&lds_h[(r + 1) * 72 + c]) = *(const v8h*)(h_in + toff + idx);
        *(v8h*)(&lds_p[r * 72 + c])       = *(const v8h*)(p16 + toff + idx);
        *(v8h*)(&lds_gt[r * 72 + c])      = *(const v8h*)(gt16 + (size_t)b * 4096 + idx);
    } else if (tid < 520) {
        *(v8h*)(&lds_h[(tid - 512) * 8]) = zero8;     // zero row 0
    } else if (tid < 528) {
        *(v8h*)(&lds_gs[(tid - 520) * 8]) = *(const v8h*)(gs16 + (size_t)blk * 64 + (tid - 520) * 8);
    }
    for (int i2 = tid; i2 < 64 * 66; i2 += 576) c_red[i2] = 0.0f;
    __syncthreads();                                  // B1

    const _Float16* segbase[7] = {lds_htb, lds_h + 72, lds_hta, lds_h, lds_p, lds_gt, lds_gs};
    const int segstride[7] = {72, 72, 72, 72, 72, 72, 0};

    int g = wave;                                     // one gate per wave
    const float* bg = bias9 + g * 4096;
    v4f acc[4][4];
#pragma unroll
    for (int mi = 0; mi < 4; ++mi)
#pragma unroll
        for (int ni = 0; ni < 4; ++ni)
#pragma unroll
            for (int i = 0; i < 4; ++i) {
                int n = mi * 16 + quad * 4 + i;
                acc[mi][ni][i] = bg[n * 64 + ni * 16 + col];
            }

    const _Float16* wg = WTh + (size_t)g * 28672;
#pragma unroll
    for (int ks = 0; ks < 14; ++ks) {
        int seg   = ks >> 1;
        int koff  = (ks & 1) * 32 + quad * 8;
        int kglob = ks * 32 + quad * 8;
        v8h bf[4];
#pragma unroll
        for (int ni = 0; ni < 4; ++ni)
            bf[ni] = *(const v8h*)(wg + (size_t)(ni * 16 + col) * 448 + kglob);
        v8h af[4];
#pragma unroll
        for (int mi = 0; mi < 4; ++mi) {
            int m = mi * 16 + col;
            af[mi] = *(const v8h*)(segbase[seg] + m * segstride[seg] + koff);
        }
#pragma unroll
        for (int mi = 0; mi < 4; ++mi)
#pragma unroll
            for (int ni = 0; ni < 4; ++ni)
                acc[mi][ni] = __builtin_amdgcn_mfma_f32_16x16x32_f16(af[mi], bf[ni], acc[mi][ni], 0, 0, 0);
    }

    // ---- per-gate epilogue (wave-uniform branches)
    if (g == 0) {                         // i_n: sigmoid -> i_lds (f16)
#pragma unroll
        for (int mi = 0; mi < 4; ++mi)
#pragma unroll
            for (int ni = 0; ni < 4; ++ni)
#pragma unroll
                for (int i = 0; i < 4; ++i) {
                    int n = mi * 16 + quad * 4 + i, kk = ni * 16 + col;
                    i_lds[n * 68 + kk] = (_Float16)sigmoid_f(acc[mi][ni][i]);
                }
    } else if (g == 7) {                  // o_n: sigmoid kept in acc regs
#pragma unroll
        for (int mi = 0; mi < 4; ++mi)
#pragma unroll
            for (int ni = 0; ni < 4; ++ni)
#pragma unroll
                for (int i = 0; i < 4; ++i)
                    acc[mi][ni][i] = sigmoid_f(acc[mi][ni][i]);
    } else if (g == 8) {                  // c_n: tanh kept in acc regs
#pragma unroll
        for (int mi = 0; mi < 4; ++mi)
#pragma unroll
            for (int ni = 0; ni < 4; ++ni)
#pragma unroll
                for (int i = 0; i < 4; ++i)
                    acc[mi][ni][i] = tanh_f(acc[mi][ni][i]);
    } else {                              // forget gates: sigmoid * partner -> c_red
        const float* pb = nullptr;
        if (g == 1)      pb = (t > 0)  ? c_in + toff - 4096 : nullptr;
        else if (g == 2 || g == 4) pb = c_in + toff;
        else if (g == 3) pb = (t < 62) ? c_in + toff + 4096 : nullptr;
        else if (g == 5) pb = gt32 + (size_t)b * 4096;
        float gsv[4];
        if (g == 6) {
            const float* gr = gs32 + (size_t)blk * 64;
#pragma unroll
            for (int ni = 0; ni < 4; ++ni) gsv[ni] = gr[ni * 16 + col];
        }
#pragma unroll
        for (int mi = 0; mi < 4; ++mi)
#pragma unroll
            for (int ni = 0; ni < 4; ++ni)
#pragma unroll
                for (int i = 0; i < 4; ++i) {
                    int n = mi * 16 + quad * 4 + i, kk = ni * 16 + col;
                    float act = sigmoid_f(acc[mi][ni][i]);
                    float val;
                    if (g == 6)      val = gsv[ni];
                    else if (g == 4) val = (n > 0) ? pb[(n - 1) * 64 + kk] : 0.0f;
                    else             val = pb ? pb[n * 64 + kk] : 0.0f;
                    atomicAdd(&c_red[n * 66 + kk], act * val);
                }
    }
    __syncthreads();                      // B2: i_lds ready, forget adds done

    if (g == 8) {                         // c_n * i_n
#pragma unroll
        for (int mi = 0; mi < 4; ++mi)
#pragma unroll
            for (int ni = 0; ni < 4; ++ni)
#pragma unroll
                for (int i = 0; i < 4; ++i) {
                    int n = mi * 16 + quad * 4 + i, kk = ni * 16 + col;
                    float iv = (float)i_lds[n * 68 + kk];
                    atomicAdd(&c_red[n * 66 + kk], acc[mi][ni][i] * iv);
                }
    }
    __syncthreads();                      // B3: c_red complete

    if (g == 7) {                         // h = o_n * tanh(c)
#pragma unroll
        for (int mi = 0; mi < 4; ++mi)
#pragma unroll
            for (int ni = 0; ni < 4; ++ni)
#pragma unroll
                for (int i = 0; i < 4; ++i) {
                    int n = mi * 16 + quad * 4 + i, kk = ni * 16 + col;
                    float hv = acc[mi][ni][i] * tanh_f(c_red[n * 66 + kk]);
                    if (last) outf[toff + n * 64 + kk] = hv;
                    else      h_out[toff + n * 64 + kk] = (_Float16)hv;
                }
    } else if (g == 0 && !last) {         // write new c
#pragma unroll
        for (int mi = 0; mi < 4; ++mi)
#pragma unroll
            for (int ni = 0; ni < 4; ++ni)
#pragma unroll
                for (int i = 0; i < 4; ++i) {
                    int n = mi * 16 + quad * 4 + i, kk = ni * 16 + col;
                    c_out[toff + n * 64 + kk] = c_red[n * 66 + kk];
                }
    }
}

// ---------------------------------------------------------------------------
extern "C" void kernel_launch(void* const* d_in, const int* in_sizes, int n_in,
                              void* d_out, int out_size, void* d_ws, size_t ws_size,
                              hipStream_t stream)
{
    const float* enc = (const float*)d_in[0];
    // d_in[1] (decoder_inputs) is unused by the reference
    const float* win = (const float*)d_in[2];
    const float* bin = (const float*)d_in[3];
    const float* U   = (const float*)d_in[4];
    const float* Wt  = (const float*)d_in[5];
    const float* Ws  = (const float*)d_in[6];
    const float* Zt  = (const float*)d_in[7];
    const float* Zs  = (const float*)d_in[8];
    const float* bb  = (const float*)d_in[9];
    float* out = (float*)d_out;
    char* ws = (char*)d_ws;

    _Float16* enc_hi = (_Float16*)(ws);                   // 16,777,216
    _Float16* enc_lo = (_Float16*)(ws + 16777216);        // 16,777,216
    _Float16* winT_h = (_Float16*)(ws + 33554432);        // 33,554,432
    _Float16* winT_l = (_Float16*)(ws + 67108864);        // 33,554,432 (dead after gemm)
    float*    c0     = (float*)   (ws + 100663296);       // 33,030,144
    _Float16* hA     = (_Float16*)(ws + 133693440);       // 16,515,072 (= p)
    float*    gt32   = (float*)   (ws + 150208512);       // 524,288
    _Float16* gt16   = (_Float16*)(ws + 150732800);       // 262,144
    float*    gs32   = (float*)   (ws + 150994944);       // 516,096
    _Float16* gs16   = (_Float16*)(ws + 151511040);       // 258,048
    _Float16* WT_h   = (_Float16*)(ws + 151769088);       // 516,096
    // hB/hC alias winT_lo space (dead after gemm_h0)
    _Float16* hB     = (_Float16*)(ws + 67108864);        // 16,515,072
    _Float16* hC     = (_Float16*)(ws + 83886080);        // 16,515,072 (ends 100,401,152 < c0)
    float* c1 = out;  // d_out doubles as the second c ping-pong buffer

    prep_wt   <<<1008, 256, 0, stream>>>(Wt, Ws, U, Zt, Zs, WT_h);
    conv_enc  <<<4096, 256, 0, stream>>>(enc, enc_hi, enc_lo);
    transp_win<<<dim3(64, 64), 256, 0, stream>>>(win, winT_h, winT_l);
    gemm_h0   <<<512, 256, 0, stream>>>(enc_hi, enc_lo, winT_h, winT_l, bin, c0, hA);
    mean_t    <<<512, 256, 0, stream>>>(c0, gt32, gt16);
    mean_n    <<<504, 256, 0, stream>>>(c0, gs32, gs16);
    recur<<<2016, 576, 0, stream>>>(hA, hB, c0, c1, hA, gt16, gs16, gt32, gs32, WT_h, bb, out, 0);
    recur<<<2016, 576, 0, stream>>>(hB, hC, c1, c0, hA, gt16, gs16, gt32, gs32, WT_h, bb, out, 0);
    recur<<<2016, 576, 0, stream>>>(hC, nullptr, c0, nullptr, hA, gt16, gs16, gt32, gs32, WT_h, bb, out, 1);
}

// Round 4
// 1286.159 us; speedup vs baseline: 4.2724x; 1.6998x over previous
//
#include <hip/hip_runtime.h>

typedef _Float16 v8h __attribute__((ext_vector_type(8)));
typedef float    v4f __attribute__((ext_vector_type(4)));

#define LO_SCALE 2048.0f
#define LO_INV   4.8828125e-4f

__device__ __forceinline__ float fast_rcp(float x) { return __builtin_amdgcn_rcpf(x); }
__device__ __forceinline__ float sigmoid_f(float x) { return fast_rcp(1.0f + __expf(-x)); }
__device__ __forceinline__ float tanh_f(float x) {
    float e = __expf(-2.0f * fabsf(x));
    float r = (1.0f - e) * fast_rcp(1.0f + e);
    return copysignf(r, x);
}

// ---------------------------------------------------------------------------
// prep: fused, transposed f16 weight matrix WT[g][kout][448]
// K segments: [Wt0 | Wt1 | Wt2 | Ws | U | Zt | Zs[ZS_IDX[g]]]
// ---------------------------------------------------------------------------
__global__ void prep_wt(const float* __restrict__ Wt, const float* __restrict__ Ws,
                        const float* __restrict__ U,  const float* __restrict__ Zt,
                        const float* __restrict__ Zs, _Float16* __restrict__ WTh)
{
    int idx = blockIdx.x * 256 + threadIdx.x;
    if (idx >= 9 * 64 * 448) return;
    int g    = idx / 28672;
    int rem  = idx - g * 28672;
    int kout = rem / 448;
    int k    = rem - kout * 448;
    int seg  = k >> 6, kl = k & 63;
    const int zsidx[9] = {0, 1, 1, 3, 4, 5, 6, 7, 8};
    float v;
    if (seg < 3)       v = Wt[g * 12288 + (seg * 64 + kl) * 64 + kout];
    else if (seg == 3) v = Ws[g * 4096 + kl * 64 + kout];
    else if (seg == 4) v = U [g * 4096 + kl * 64 + kout];
    else if (seg == 5) v = Zt[g * 4096 + kl * 64 + kout];
    else               v = Zs[zsidx[g] * 4096 + kl * 64 + kout];
    WTh[idx] = (_Float16)v;
}

// ---------------------------------------------------------------------------
// f32 -> f16 hi/lo split of encoder inputs, zero-padded to 2048 rows
// ---------------------------------------------------------------------------
__global__ void conv_enc(const float* __restrict__ X,
                         _Float16* __restrict__ Yh, _Float16* __restrict__ Yl)
{
    long i = ((long)blockIdx.x * 256 + threadIdx.x) * 8;   // < 2048*4096
    v8h oh, ol;
    if (i < 2016L * 4096) {
        const float4* p = (const float4*)(X + i);
        float4 a = p[0], b = p[1];
        float xv[8] = {a.x, a.y, a.z, a.w, b.x, b.y, b.z, b.w};
#pragma unroll
        for (int j = 0; j < 8; ++j) {
            _Float16 hi = (_Float16)xv[j];
            oh[j] = hi;
            ol[j] = (_Float16)((xv[j] - (float)hi) * LO_SCALE);
        }
    } else {
#pragma unroll
        for (int j = 0; j < 8; ++j) { oh[j] = (_Float16)0.0f; ol[j] = (_Float16)0.0f; }
    }
    *(v8h*)(Yh + i) = oh;
    *(v8h*)(Yl + i) = ol;
}

// ---------------------------------------------------------------------------
// transpose weights_in [k][n] f32 -> winT hi/lo [n][k] f16
// ---------------------------------------------------------------------------
__global__ void transp_win(const float* __restrict__ W,
                           _Float16* __restrict__ Th, _Float16* __restrict__ Tl)
{
    __shared__ float tile[64][65];
    int k0 = blockIdx.x * 64, n0 = blockIdx.y * 64;
    int tid = threadIdx.x;
    int cc = tid & 63;
#pragma unroll
    for (int p = 0; p < 16; ++p) {
        int r = p * 4 + (tid >> 6);
        tile[cc][r] = W[(size_t)(k0 + r) * 4096 + n0 + cc];
    }
    __syncthreads();
#pragma unroll
    for (int p = 0; p < 16; ++p) {
        int r = p * 4 + (tid >> 6);
        float v = tile[r][cc];
        _Float16 hi = (_Float16)v;
        Th[(size_t)(n0 + r) * 4096 + k0 + cc] = hi;
        Tl[(size_t)(n0 + r) * 4096 + k0 + cc] = (_Float16)((v - (float)hi) * LO_SCALE);
    }
}

// ---------------------------------------------------------------------------
// h0 = enc @ winT^T + bias, compensated 3-pass f16 MFMA (f32-exact result)
// 128x128 tile, BK=32; writes f32 (c0) and f16 (hA)
// ---------------------------------------------------------------------------
__global__ __launch_bounds__(256, 2) void gemm_h0(
    const _Float16* __restrict__ Ah, const _Float16* __restrict__ Al,
    const _Float16* __restrict__ Bh, const _Float16* __restrict__ Bl,
    const float* __restrict__ bias, float* __restrict__ h0f, _Float16* __restrict__ h0h)
{
    __shared__ __attribute__((aligned(16))) _Float16 Ash[128 * 40];
    __shared__ __attribute__((aligned(16))) _Float16 Asl[128 * 40];
    __shared__ __attribute__((aligned(16))) _Float16 Bsh[128 * 40];
    __shared__ __attribute__((aligned(16))) _Float16 Bsl[128 * 40];
    int id = blockIdx.x;                 // 0..511
    int xcd = id & 7, local = id >> 3;   // local 0..63
    int nt = xcd * 4 + (local >> 4);     // 0..31
    int mt = local & 15;                 // 0..15
    int tid = threadIdx.x, wave = tid >> 6, lane = tid & 63;
    int col = lane & 15, quad = lane >> 4;

    v4f accm[2][8], accc[2][8];
#pragma unroll
    for (int mi = 0; mi < 2; ++mi)
#pragma unroll
        for (int ni = 0; ni < 8; ++ni) {
            v4f z = {0.f, 0.f, 0.f, 0.f};
            accm[mi][ni] = z; accc[mi][ni] = z;
        }

    for (int kt = 0; kt < 128; ++kt) {
        __syncthreads();
#pragma unroll
        for (int p = 0; p < 2; ++p) {
            int idx = p * 2048 + tid * 8;
            int r = idx >> 5, c = idx & 31;
            size_t ga = (size_t)(mt * 128 + r) * 4096 + kt * 32 + c;
            size_t gb = (size_t)(nt * 128 + r) * 4096 + kt * 32 + c;
            *(v8h*)(&Ash[r * 40 + c]) = *(const v8h*)(Ah + ga);
            *(v8h*)(&Asl[r * 40 + c]) = *(const v8h*)(Al + ga);
            *(v8h*)(&Bsh[r * 40 + c]) = *(const v8h*)(Bh + gb);
            *(v8h*)(&Bsl[r * 40 + c]) = *(const v8h*)(Bl + gb);
        }
        __syncthreads();
        v8h afh[2], afl[2];
#pragma unroll
        for (int mi = 0; mi < 2; ++mi) {
            afh[mi] = *(const v8h*)(&Ash[(wave * 32 + mi * 16 + col) * 40 + quad * 8]);
            afl[mi] = *(const v8h*)(&Asl[(wave * 32 + mi * 16 + col) * 40 + quad * 8]);
        }
#pragma unroll
        for (int ni = 0; ni < 8; ++ni) {
            v8h bfh = *(const v8h*)(&Bsh[(ni * 16 + col) * 40 + quad * 8]);
            v8h bfl = *(const v8h*)(&Bsl[(ni * 16 + col) * 40 + quad * 8]);
#pragma unroll
            for (int mi = 0; mi < 2; ++mi) {
                accm[mi][ni] = __builtin_amdgcn_mfma_f32_16x16x32_f16(afh[mi], bfh, accm[mi][ni], 0, 0, 0);
                accc[mi][ni] = __builtin_amdgcn_mfma_f32_16x16x32_f16(afl[mi], bfh, accc[mi][ni], 0, 0, 0);
                accc[mi][ni] = __builtin_amdgcn_mfma_f32_16x16x32_f16(afh[mi], bfl, accc[mi][ni], 0, 0, 0);
            }
        }
    }
#pragma unroll
    for (int mi = 0; mi < 2; ++mi)
#pragma unroll
        for (int ni = 0; ni < 8; ++ni)
#pragma unroll
            for (int i = 0; i < 4; ++i) {
                int row  = mt * 128 + wave * 32 + mi * 16 + quad * 4 + i;
                int ccol = nt * 128 + ni * 16 + col;
                if (row < 2016) {
                    float v = accm[mi][ni][i] + accc[mi][ni][i] * LO_INV + bias[ccol];
                    h0f[(size_t)row * 4096 + ccol] = v;
                    h0h[(size_t)row * 4096 + ccol] = (_Float16)v;
                }
            }
}

// ---------------------------------------------------------------------------
// g_t = mean over t (63);  g_s = mean over n (64)
// ---------------------------------------------------------------------------
__global__ void mean_t(const float* __restrict__ h0, float* __restrict__ gt32,
                       _Float16* __restrict__ gt16)
{
    int i = blockIdx.x * 256 + threadIdx.x;       // < 32*4096
    int b = i >> 12, c = i & 4095;
    float s = 0.f;
    for (int t = 0; t < 63; ++t) s += h0[((size_t)b * 63 + t) * 4096 + c];
    s *= (1.0f / 63.0f);
    gt32[i] = s; gt16[i] = (_Float16)s;
}

__global__ void mean_n(const float* __restrict__ h0, float* __restrict__ gs32,
                       _Float16* __restrict__ gs16)
{
    int i = blockIdx.x * 256 + threadIdx.x;       // < 2016*64
    int row = i >> 6, k = i & 63;
    float s = 0.f;
    for (int n = 0; n < 64; ++n) s += h0[(size_t)row * 4096 + n * 64 + k];
    s *= (1.0f / 64.0f);
    gs32[i] = s; gs16[i] = (_Float16)s;
}

// ---------------------------------------------------------------------------
// fused recurrent step, k-split: block = 4 waves per (b,t) tile; each wave
// owns a 64x16 k-slice and runs ALL 9 gates sequentially with the cell sum
// held in registers. No LDS reduction, no atomics, one barrier, no spills.
// A segs: [h(t-1) | h(t) | h(t+1) | h(n-1) | p | g_t(global) | g_s(global)]
// ---------------------------------------------------------------------------
__global__ __launch_bounds__(256, 4) void recur(
    const _Float16* __restrict__ h_in, _Float16* __restrict__ h_out,
    const float* __restrict__ c_in, float* __restrict__ c_out,
    const _Float16* __restrict__ p16, const _Float16* __restrict__ gt16,
    const _Float16* __restrict__ gs16, const float* __restrict__ gt32,
    const float* __restrict__ gs32, const _Float16* __restrict__ WTh,
    const float* __restrict__ bias9, float* __restrict__ outf, int last)
{
    __shared__ __attribute__((aligned(16))) _Float16 lds_htb[64 * 72];
    __shared__ __attribute__((aligned(16))) _Float16 lds_h  [65 * 72];   // row 0 = zeros
    __shared__ __attribute__((aligned(16))) _Float16 lds_hta[64 * 72];
    __shared__ __attribute__((aligned(16))) _Float16 lds_p  [64 * 72];

    int blk = blockIdx.x;
    int b = blk / 63, t = blk - b * 63;
    size_t toff = (size_t)blk * 4096;
    int tid = threadIdx.x;
    int wave = tid >> 6, lane = tid & 63;
    int col = lane & 15, quad = lane >> 4;
    int k0 = wave * 16;                  // this wave's k-slice

    v8h zero8;
#pragma unroll
    for (int j = 0; j < 8; ++j) zero8[j] = (_Float16)0.0f;

    // ---- stage h(t-1), h(t), h(t+1), p into LDS (stride 72: 2-way = free)
    {
        const _Float16* s_htb = (t > 0)  ? h_in + toff - 4096 : nullptr;
        const _Float16* s_hta = (t < 62) ? h_in + toff + 4096 : nullptr;
#pragma unroll
        for (int p2 = 0; p2 < 2; ++p2) {
            int idx = p2 * 2048 + tid * 8;
            int r = idx >> 6, c = idx & 63;
            v8h v;
            v = s_htb ? *(const v8h*)(s_htb + idx) : zero8;
            *(v8h*)(&lds_htb[r * 72 + c]) = v;
            v = s_hta ? *(const v8h*)(s_hta + idx) : zero8;
            *(v8h*)(&lds_hta[r * 72 + c]) = v;
            *(v8h*)(&lds_h[(r + 1) * 72 + c]) = *(const v8h*)(h_in + toff + idx);
            *(v8h*)(&lds_p[r * 72 + c])       = *(const v8h*)(p16 + toff + idx);
        }
        if (tid < 8) *(v8h*)(&lds_h[tid * 8]) = zero8;    // zero row 0
    }
    __syncthreads();

    const _Float16* seglds[5] = {lds_htb, lds_h + 72, lds_hta, lds_h, lds_p};
    const _Float16* gtb = gt16 + (size_t)b * 4096;
    const _Float16* gsb = gs16 + (size_t)blk * 64;

    v4f csum[4], istash[4];
#pragma unroll
    for (int mi = 0; mi < 4; ++mi) {
        v4f z = {0.f, 0.f, 0.f, 0.f};
        csum[mi] = z; istash[mi] = z;
    }

    // gate order: 0(i), 1..6(forget), 8(c_n*i), 7(o -> h)
#pragma unroll
    for (int gi = 0; gi < 9; ++gi) {
        int g = (gi == 7) ? 8 : ((gi == 8) ? 7 : gi);
        const _Float16* wg = WTh + (size_t)g * 28672 + (size_t)k0 * 448;
        const float* bg = bias9 + g * 4096;

        v4f acc[4];
#pragma unroll
        for (int mi = 0; mi < 4; ++mi)
#pragma unroll
            for (int i = 0; i < 4; ++i)
                acc[mi][i] = bg[(mi * 16 + quad * 4 + i) * 64 + k0 + col];

#pragma unroll
        for (int ks = 0; ks < 14; ++ks) {
            int seg  = ks >> 1;
            int koff = (ks & 1) * 32 + quad * 8;
            v8h bf = *(const v8h*)(wg + (size_t)col * 448 + ks * 32 + quad * 8);
            v8h af[4];
            if (seg < 5) {
#pragma unroll
                for (int mi = 0; mi < 4; ++mi)
                    af[mi] = *(const v8h*)(seglds[seg] + (mi * 16 + col) * 72 + koff);
            } else if (seg == 5) {
#pragma unroll
                for (int mi = 0; mi < 4; ++mi)
                    af[mi] = *(const v8h*)(gtb + (mi * 16 + col) * 64 + koff);
            } else {
                v8h gv = *(const v8h*)(gsb + koff);     // broadcast over rows
#pragma unroll
                for (int mi = 0; mi < 4; ++mi) af[mi] = gv;
            }
#pragma unroll
            for (int mi = 0; mi < 4; ++mi)
                acc[mi] = __builtin_amdgcn_mfma_f32_16x16x32_f16(af[mi], bf, acc[mi], 0, 0, 0);
        }

        // ---- epilogue for this gate (branches fold: g is compile-time)
        if (g == 0) {
#pragma unroll
            for (int mi = 0; mi < 4; ++mi)
#pragma unroll
                for (int i = 0; i < 4; ++i)
                    istash[mi][i] = sigmoid_f(acc[mi][i]);
        } else if (g == 8) {
#pragma unroll
            for (int mi = 0; mi < 4; ++mi)
#pragma unroll
                for (int i = 0; i < 4; ++i)
                    csum[mi][i] += tanh_f(acc[mi][i]) * istash[mi][i];
        } else if (g == 7) {
#pragma unroll
            for (int mi = 0; mi < 4; ++mi)
#pragma unroll
                for (int i = 0; i < 4; ++i) {
                    int n = mi * 16 + quad * 4 + i, kk = k0 + col;
                    float hv = sigmoid_f(acc[mi][i]) * tanh_f(csum[mi][i]);
                    if (last) outf[toff + n * 64 + kk] = hv;
                    else      h_out[toff + n * 64 + kk] = (_Float16)hv;
                }
        } else {                          // forget gates 1..6
#pragma unroll
            for (int mi = 0; mi < 4; ++mi)
#pragma unroll
                for (int i = 0; i < 4; ++i) {
                    int n = mi * 16 + quad * 4 + i, kk = k0 + col;
                    float val;
                    if (g == 1)      val = (t > 0)  ? c_in[toff - 4096 + n * 64 + kk] : 0.0f;
                    else if (g == 2) val = c_in[toff + n * 64 + kk];
                    else if (g == 3) val = (t < 62) ? c_in[toff + 4096 + n * 64 + kk] : 0.0f;
                    else if (g == 4) val = (n > 0)  ? c_in[toff + (n - 1) * 64 + kk] : 0.0f;
                    else if (g == 5) val = gt32[(size_t)b * 4096 + n * 64 + kk];
                    else             val = gs32[(size_t)blk * 64 + kk];
                    csum[mi][i] += sigmoid_f(acc[mi][i]) * val;
                }
        }
    }

    if (!last) {                          // write new c (each wave its slice)
#pragma unroll
        for (int mi = 0; mi < 4; ++mi)
#pragma unroll
            for (int i = 0; i < 4; ++i) {
                int n = mi * 16 + quad * 4 + i, kk = k0 + col;
                c_out[toff + n * 64 + kk] = csum[mi][i];
            }
    }
}

// ---------------------------------------------------------------------------
extern "C" void kernel_launch(void* const* d_in, const int* in_sizes, int n_in,
                              void* d_out, int out_size, void* d_ws, size_t ws_size,
                              hipStream_t stream)
{
    const float* enc = (const float*)d_in[0];
    // d_in[1] (decoder_inputs) is unused by the reference
    const float* win = (const float*)d_in[2];
    const float* bin = (const float*)d_in[3];
    const float* U   = (const float*)d_in[4];
    const float* Wt  = (const float*)d_in[5];
    const float* Ws  = (const float*)d_in[6];
    const float* Zt  = (const float*)d_in[7];
    const float* Zs  = (const float*)d_in[8];
    const float* bb  = (const float*)d_in[9];
    float* out = (float*)d_out;
    char* ws = (char*)d_ws;

    _Float16* enc_hi = (_Float16*)(ws);                   // 16,777,216
    _Float16* enc_lo = (_Float16*)(ws + 16777216);        // 16,777,216
    _Float16* winT_h = (_Float16*)(ws + 33554432);        // 33,554,432
    _Float16* winT_l = (_Float16*)(ws + 67108864);        // 33,554,432 (dead after gemm)
    float*    c0     = (float*)   (ws + 100663296);       // 33,030,144
    _Float16* hA     = (_Float16*)(ws + 133693440);       // 16,515,072 (= p)
    float*    gt32   = (float*)   (ws + 150208512);       // 524,288
    _Float16* gt16   = (_Float16*)(ws + 150732800);       // 262,144
    float*    gs32   = (float*)   (ws + 150994944);       // 516,096
    _Float16* gs16   = (_Float16*)(ws + 151511040);       // 258,048
    _Float16* WT_h   = (_Float16*)(ws + 151769088);       // 516,096
    // hB/hC alias winT_lo space (dead after gemm_h0)
    _Float16* hB     = (_Float16*)(ws + 67108864);        // 16,515,072
    _Float16* hC     = (_Float16*)(ws + 83886080);        // 16,515,072 (ends 100,401,152 < c0)
    float* c1 = out;  // d_out doubles as the second c ping-pong buffer

    prep_wt   <<<1008, 256, 0, stream>>>(Wt, Ws, U, Zt, Zs, WT_h);
    conv_enc  <<<4096, 256, 0, stream>>>(enc, enc_hi, enc_lo);
    transp_win<<<dim3(64, 64), 256, 0, stream>>>(win, winT_h, winT_l);
    gemm_h0   <<<512, 256, 0, stream>>>(enc_hi, enc_lo, winT_h, winT_l, bin, c0, hA);
    mean_t    <<<512, 256, 0, stream>>>(c0, gt32, gt16);
    mean_n    <<<504, 256, 0, stream>>>(c0, gs32, gs16);
    recur<<<2016, 256, 0, stream>>>(hA, hB, c0, c1, hA, gt16, gs16, gt32, gs32, WT_h, bb, out, 0);
    recur<<<2016, 256, 0, stream>>>(hB, hC, c1, c0, hA, gt16, gs16, gt32, gs32, WT_h, bb, out, 0);
    recur<<<2016, 256, 0, stream>>>(hC, nullptr, c0, nullptr, hA, gt16, gs16, gt32, gs32, WT_h, bb, out, 1);
}